// Round 3
// baseline (569.618 us; speedup 1.0000x reference)
//
#include <hip/hip_runtime.h>

// TopK-mask: per row of [16384, 4096] f32, keep the 64 largest, zero the rest.
// 256-thread blocks; keys = order-preserving uint32 transform.
// Radix select, digits 11+11+10 (MSB first), LDS histograms 2048/2048/1024 bins.
// Ties at the K-th value: lowest index wins (matches jax.lax.top_k).
//
// R6: persistent blocks + cross-row register prefetch.
//   Occupancy is already HW-max (18.5 KB LDS x 8 blocks/CU, 32 waves/CU), yet
//   per-round time (~15 us) exceeds the memory floor (~10.7 us). Theory:
//   identical blocks convoy — during the barrier-serialized select phases the
//   memory pipe idles. Fix: each block owns 8 consecutive rows; right after
//   transforming row r's raw float4s into keys, it issues row r+1's loads into
//   the freed raw registers. Every block then has 16 KB of loads in flight
//   across its whole compute phase, keeping HBM busy regardless of phase
//   alignment. Peak live regs unchanged (keys[16]+raw[16], same as before).
//
// R5 (kept): lane-contiguous float4 load/store (xv[t+256c]); tie-rank scan
//   off the common path (need==h at the threshold bin => inclusion is k>=T);
//   exact tie-break on a block-uniform rare path, (c,t,j) index order.
//
// NOTE (R4 lesson): __builtin_nontemporal_store on the output REGRESSED 3x —
// WRITE_SIZE 262MB -> 711MB. gfx950 'nt' bypasses L2 write-combining. Plain
// stores only.

#define COLS 4096
#define KTOP 64u
#define NT 256
#define EPT 16            // elements per thread (COLS / NT)
#define RPB 8             // rows per persistent block (16384 / 2048)
#define H11 2304          // 2048 bins + (b>>3) padding
#define H10 1280          // 1024 bins + (b>>2) padding (reuses region A)

__device__ __forceinline__ unsigned pad8(unsigned b) { return b + (b >> 3); }
__device__ __forceinline__ unsigned pad4(unsigned b) { return b + (b >> 2); }

__global__ __launch_bounds__(NT, 8) void topk_mask_kernel(const float* __restrict__ x,
                                                          float* __restrict__ out) {
    const int t = threadIdx.x;
    const unsigned lane = t & 63u;
    const unsigned w = t >> 6;
    const int row0 = blockIdx.x * RPB;

    __shared__ alignas(16) unsigned histmem[2 * H11];  // A: [0,H11)  B: [H11,2*H11)
    __shared__ unsigned scw[4], scw2[4];
    __shared__ unsigned sh_selbin, sh_selS, sh_selH;

    unsigned* histA = histmem;
    unsigned* histB = histmem + H11;

    // ---- Prologue: issue row0's loads (lane-contiguous float4) ----
    float4 raw[4];
    {
        const float4* xv = reinterpret_cast<const float4*>(x + (size_t)row0 * COLS);
        #pragma unroll
        for (int c = 0; c < 4; ++c) raw[c] = xv[t + NT * c];
    }

    for (int r = 0; r < RPB; ++r) {
        const int row = row0 + r;
        float* __restrict__ orow = out + (size_t)row * COLS;

        // ---- Transform raw -> sortable keys (raw regs die here) ----
        // Global element index of key[4c+j] is 1024*c + 4*t + j.
        unsigned key[EPT];
        #pragma unroll
        for (int c = 0; c < 4; ++c) {
            float f[4] = {raw[c].x, raw[c].y, raw[c].z, raw[c].w};
            #pragma unroll
            for (int j = 0; j < 4; ++j) {
                unsigned u = __float_as_uint(f[j]);
                key[4 * c + j] = (u & 0x80000000u) ? ~u : (u | 0x80000000u);
            }
        }

        // ---- Prefetch next row into the freed raw regs; overlaps the whole
        //      select+store phase below (the block's own memory-pipe work) ----
        if (r + 1 < RPB) {
            const float4* xn = reinterpret_cast<const float4*>(x + (size_t)(row + 1) * COLS);
            #pragma unroll
            for (int c = 0; c < 4; ++c) raw[c] = xn[t + NT * c];
        }

        // ---- Zero both histogram regions, vectorized ----
        {
            uint4* hz = reinterpret_cast<uint4*>(histmem);
            #pragma unroll
            for (int i = 0; i < 5; ++i) {
                unsigned idx = t + NT * i;
                if (idx < (2 * H11) / 4) hz[idx] = make_uint4(0u, 0u, 0u, 0u);
            }
        }
        __syncthreads();                                               // B1

        unsigned need = KTOP;
        unsigned prefix = 0;
        unsigned T = 0;

        // ================= Pass 0: 2048 bins over key[31:21] =================
        #pragma unroll
        for (int j = 0; j < EPT; ++j) atomicAdd(&histA[pad8(key[j] >> 21)], 1u);
        __syncthreads();                                               // B2
        {
            unsigned hr[8];
            unsigned L = 0;
            const unsigned base = 9u * t;         // pad8(8t+i) = 9t+i, i<8
            #pragma unroll
            for (int i = 0; i < 8; ++i) { hr[i] = histA[base + i]; L += hr[i]; }

            unsigned suf = L;                     // intra-wave inclusive suffix scan
            #pragma unroll
            for (int d = 1; d < 64; d <<= 1) {
                unsigned o = __shfl_down(suf, d, 64);
                if (lane + d < 64) suf += o;
            }
            if (lane == 0) scw[w] = suf;          // wave total
            __syncthreads();                                           // B3
            unsigned S = suf - L;                 // excl suffix within wave
            #pragma unroll
            for (int w2 = 1; w2 < 4; ++w2) if (w2 > (int)w) S += scw[w2];

            #pragma unroll
            for (int i = 7; i >= 0; --i) {
                unsigned h = hr[i], Sn = S + h;
                if (S < need && need <= Sn) { sh_selbin = 8u * t + i; sh_selS = S; }
                S = Sn;
            }
            __syncthreads();                                           // B4
            prefix = sh_selbin;                   // 11-bit prefix
            need -= sh_selS;
        }

        // ======== Pass 1: 2048 bins over key[20:10], prefix-filtered ========
        {
            // concurrently re-zero region A's first H10 words for pass 2
            uint4* hzA = reinterpret_cast<uint4*>(histA);
            #pragma unroll
            for (int i = 0; i < 2; ++i) {
                unsigned idx = t + NT * i;
                if (idx < H10 / 4) hzA[idx] = make_uint4(0u, 0u, 0u, 0u);
            }
            #pragma unroll
            for (int j = 0; j < EPT; ++j) {
                unsigned k = key[j];
                if ((k >> 21) == prefix) atomicAdd(&histB[pad8((k >> 10) & 0x7FFu)], 1u);
            }
            __syncthreads();                                           // B5

            unsigned hr[8];
            unsigned L = 0;
            const unsigned base = 9u * t;
            #pragma unroll
            for (int i = 0; i < 8; ++i) { hr[i] = histB[base + i]; L += hr[i]; }

            unsigned suf = L;
            #pragma unroll
            for (int d = 1; d < 64; d <<= 1) {
                unsigned o = __shfl_down(suf, d, 64);
                if (lane + d < 64) suf += o;
            }
            if (lane == 0) scw[w] = suf;
            __syncthreads();                                           // B6
            unsigned S = suf - L;
            #pragma unroll
            for (int w2 = 1; w2 < 4; ++w2) if (w2 > (int)w) S += scw[w2];

            #pragma unroll
            for (int i = 7; i >= 0; --i) {
                unsigned h = hr[i], Sn = S + h;
                if (S < need && need <= Sn) { sh_selbin = 8u * t + i; sh_selS = S; }
                S = Sn;
            }
            __syncthreads();                                           // B7
            prefix = (prefix << 11) | sh_selbin;  // 22-bit prefix
            need -= sh_selS;
        }

        // ======== Pass 2: 1024 bins over key[9:0], prefix-filtered ========
        {
            #pragma unroll
            for (int j = 0; j < EPT; ++j) {
                unsigned k = key[j];
                if ((k >> 10) == prefix) atomicAdd(&histA[pad4(k & 0x3FFu)], 1u);
            }
            __syncthreads();                                           // B8

            unsigned hr[4];
            unsigned L = 0;
            const unsigned base = 5u * t;         // pad4(4t+i) = 5t+i, i<4
            #pragma unroll
            for (int i = 0; i < 4; ++i) { hr[i] = histA[base + i]; L += hr[i]; }

            unsigned suf = L;
            #pragma unroll
            for (int d = 1; d < 64; d <<= 1) {
                unsigned o = __shfl_down(suf, d, 64);
                if (lane + d < 64) suf += o;
            }
            if (lane == 0) scw[w] = suf;
            __syncthreads();                                           // B9
            unsigned S = suf - L;
            #pragma unroll
            for (int w2 = 1; w2 < 4; ++w2) if (w2 > (int)w) S += scw[w2];

            #pragma unroll
            for (int i = 3; i >= 0; --i) {
                unsigned h = hr[i], Sn = S + h;
                if (S < need && need <= Sn) { sh_selbin = 4u * t + i; sh_selS = S; sh_selH = h; }
                S = Sn;
            }
            __syncthreads();                                           // B10
            T = (prefix << 10) | sh_selbin;       // full 32-bit threshold key
            need -= sh_selS;
        }
        const unsigned hsel = sh_selH;            // count of key == T in the row

        float4* ov = reinterpret_cast<float4*>(orow);

        if (need == hsel) {
            // ---- Common path (always, for distinct values): every tied
            // element is included, so inclusion is simply key >= T.
            #pragma unroll
            for (int c = 0; c < 4; ++c) {
                float rr[4];
                #pragma unroll
                for (int j = 0; j < 4; ++j) {
                    unsigned k = key[4 * c + j];
                    unsigned u = (k & 0x80000000u) ? (k ^ 0x80000000u) : ~k;
                    rr[j] = (k >= T) ? __uint_as_float(u) : 0.0f;
                }
                float4 o4;
                o4.x = rr[0]; o4.y = rr[1]; o4.z = rr[2]; o4.w = rr[3];
                ov[t + NT * c] = o4;   // plain store: L2 write-combines
            }
        } else {
            // ---- Rare exact tie-break: first `need` of the key==T elements
            // by global index, (c, t, j) lexicographic. Block-uniform branch,
            // so the barrier below is safe.
            unsigned eqc[4];
            #pragma unroll
            for (int c = 0; c < 4; ++c) {
                unsigned e = 0;
                #pragma unroll
                for (int j = 0; j < 4; ++j) e += (key[4 * c + j] == T) ? 1u : 0u;
                eqc[c] = e;
            }
            // pack per-chunk counts into 16-bit fields; block sums < 2^16
            unsigned p0 = eqc[0] | (eqc[1] << 16);
            unsigned p1 = eqc[2] | (eqc[3] << 16);
            unsigned s0 = p0, s1 = p1;            // intra-wave inclusive prefix
            #pragma unroll
            for (int d = 1; d < 64; d <<= 1) {
                unsigned o0 = __shfl_up(s0, d, 64);
                unsigned o1 = __shfl_up(s1, d, 64);
                if (lane >= (unsigned)d) { s0 += o0; s1 += o1; }
            }
            if (lane == 63) { scw[w] = s0; scw2[w] = s1; }
            __syncthreads();                                           // B11 (rare)
            unsigned e0 = s0 - p0, e1 = s1 - p1;  // exclusive within block
            #pragma unroll
            for (int w2 = 0; w2 < 3; ++w2) if (w2 < (int)w) { e0 += scw[w2]; e1 += scw2[w2]; }
            unsigned tot0 = scw[0] + scw[1] + scw[2] + scw[3];
            unsigned tot1 = scw2[0] + scw2[1] + scw2[2] + scw2[3];
            const unsigned totc[4]  = { tot0 & 0xFFFFu, tot0 >> 16, tot1 & 0xFFFFu, tot1 >> 16 };
            const unsigned exclc[4] = { e0 & 0xFFFFu,   e0 >> 16,   e1 & 0xFFFFu,   e1 >> 16 };

            unsigned base = 0;
            #pragma unroll
            for (int c = 0; c < 4; ++c) {
                unsigned rank = base + exclc[c];  // rank of first equal in chunk c
                float rr[4];
                #pragma unroll
                for (int j = 0; j < 4; ++j) {
                    unsigned k = key[4 * c + j];
                    bool inc;
                    if (k > T)       inc = true;
                    else if (k == T) { inc = (rank < need); rank += 1u; }
                    else             inc = false;
                    unsigned u = (k & 0x80000000u) ? (k ^ 0x80000000u) : ~k;
                    rr[j] = inc ? __uint_as_float(u) : 0.0f;
                }
                float4 o4;
                o4.x = rr[0]; o4.y = rr[1]; o4.z = rr[2]; o4.w = rr[3];
                ov[t + NT * c] = o4;
                base += totc[c];
            }
        }
        // Re-use of histmem/sh_*/scw next iteration is race-free: after B10
        // no thread touches histmem, and sh_*/scw are only rewritten after
        // next-row barriers B3+, which every thread reaches only after B10.
    }
}

extern "C" void kernel_launch(void* const* d_in, const int* in_sizes, int n_in,
                              void* d_out, int out_size, void* d_ws, size_t ws_size,
                              hipStream_t stream) {
    const float* x = (const float*)d_in[0];
    float* out = (float*)d_out;
    const int rows = in_sizes[0] / COLS;  // 16384
    topk_mask_kernel<<<rows / RPB, NT, 0, stream>>>(x, out);
}

// Round 4
// 503.153 us; speedup vs baseline: 1.1321x; 1.1321x over previous
//
#include <hip/hip_runtime.h>

// TopK-mask: per row of [16384, 4096] f32, keep the 64 largest, zero the rest.
// 256-thread blocks; keys = order-preserving uint32 transform.
// Radix select, digits 11+11+10 (MSB first), LDS histograms 2048/2048/1024 bins.
// Ties at the K-th value: lowest index wins (matches jax.lax.top_k).
//
// R7: persistent blocks + register prefetch, done right this time.
//   R6's counters exposed two implementation bugs, not a theory failure:
//   (a) VGPR_Count=32 => the allocator spilled key[]+raw[] to scratch under
//       launch_bounds(256,8)'s 64-VGPR cap. Scratch = HBM: WRITE_SIZE 547MB
//       vs 268 ideal, FETCH 381MB vs 268. Fix: launch_bounds(256,6) (~84 VGPR
//       cap, live set ~60). LDS still permits 8 blocks/CU; VGPRs set
//       residency at 6-7 blocks. No spill.
//   (b) __syncthreads() emits s_waitcnt vmcnt(0) before s_barrier (HIP
//       semantics), so R6's prefetch was force-drained at B1 — zero overlap.
//       Fix: all select-phase barriers only order LDS, so use raw
//       s_waitcnt lgkmcnt(0) + __builtin_amdgcn_s_barrier(). Prefetch loads
//       now stay in flight across the whole select phase; the compiler's
//       vmcnt wait lands at the next row's transform (stores queue behind).
//   Rare tie path rewritten register-light (serial thread-0 scan in LDS) to
//   keep loop-level pressure down; it is never taken for random-normal data.
//
// R5 (kept): lane-contiguous float4 load/store; tie-rank scan off the common
//   path (need==h at threshold bin => inclusion is key>=T).
//
// NOTE (R4 lesson): __builtin_nontemporal_store REGRESSED 3x (WRITE_SIZE
// 262->711MB). Plain stores only.

#define COLS 4096
#define KTOP 64u
#define NT 256
#define EPT 16            // elements per thread (COLS / NT)
#define RPB 4             // rows per persistent block (16384 / 4096)
#define H11 2304          // 2048 bins + (b>>3) padding
#define H10 1280          // 1024 bins + (b>>2) padding (reuses region A)

// LDS-only barrier: orders LDS ops without draining vmcnt, so global-memory
// prefetch loads survive across it. Leading asm: own LDS writes complete
// before signaling; trailing empty asm: pins post-barrier LDS reads.
#define BAR() do {                                        \
    asm volatile("s_waitcnt lgkmcnt(0)" ::: "memory");    \
    __builtin_amdgcn_s_barrier();                         \
    asm volatile("" ::: "memory");                        \
} while (0)

__device__ __forceinline__ unsigned pad8(unsigned b) { return b + (b >> 3); }
__device__ __forceinline__ unsigned pad4(unsigned b) { return b + (b >> 2); }

__global__ __launch_bounds__(NT, 6) void topk_mask_kernel(const float* __restrict__ x,
                                                          float* __restrict__ out) {
    const int t = threadIdx.x;
    const unsigned lane = t & 63u;
    const unsigned w = t >> 6;
    const int row0 = blockIdx.x * RPB;

    __shared__ alignas(16) unsigned histmem[2 * H11];  // A: [0,H11)  B: [H11,2*H11)
    __shared__ unsigned scw[4];
    __shared__ unsigned sh_selbin, sh_selS, sh_selH;

    unsigned* histA = histmem;
    unsigned* histB = histmem + H11;

    // ---- Prologue: issue row0's loads (lane-contiguous float4) ----
    float4 raw[4];
    {
        const float4* xv = reinterpret_cast<const float4*>(x + (size_t)row0 * COLS);
        #pragma unroll
        for (int c = 0; c < 4; ++c) raw[c] = xv[t + NT * c];
    }

    for (int r = 0; r < RPB; ++r) {
        const int row = row0 + r;
        float* __restrict__ orow = out + (size_t)row * COLS;

        // ---- Transform raw -> sortable keys (raw regs die here) ----
        // Global element index of key[4c+j] is 1024*c + 4*t + j.
        unsigned key[EPT];
        #pragma unroll
        for (int c = 0; c < 4; ++c) {
            float f[4] = {raw[c].x, raw[c].y, raw[c].z, raw[c].w};
            #pragma unroll
            for (int j = 0; j < 4; ++j) {
                unsigned u = __float_as_uint(f[j]);
                key[4 * c + j] = (u & 0x80000000u) ? ~u : (u | 0x80000000u);
            }
        }

        // ---- Prefetch next row into freed raw regs. With LDS-only barriers
        //      below, these 4 dwordx4 loads stay in flight across the entire
        //      select phase (the compiler's vmcnt wait lands at the next
        //      row's transform). ----
        if (r + 1 < RPB) {
            const float4* xn = reinterpret_cast<const float4*>(x + (size_t)(row + 1) * COLS);
            #pragma unroll
            for (int c = 0; c < 4; ++c) raw[c] = xn[t + NT * c];
        }

        // ---- Zero both histogram regions, vectorized ----
        {
            uint4* hz = reinterpret_cast<uint4*>(histmem);
            #pragma unroll
            for (int i = 0; i < 5; ++i) {
                unsigned idx = t + NT * i;
                if (idx < (2 * H11) / 4) hz[idx] = make_uint4(0u, 0u, 0u, 0u);
            }
        }
        BAR();                                                         // B1

        unsigned need = KTOP;
        unsigned prefix = 0;
        unsigned T = 0;

        // ================= Pass 0: 2048 bins over key[31:21] =================
        #pragma unroll
        for (int j = 0; j < EPT; ++j) atomicAdd(&histA[pad8(key[j] >> 21)], 1u);
        BAR();                                                         // B2
        {
            unsigned hr[8];
            unsigned L = 0;
            const unsigned base = 9u * t;         // pad8(8t+i) = 9t+i, i<8
            #pragma unroll
            for (int i = 0; i < 8; ++i) { hr[i] = histA[base + i]; L += hr[i]; }

            unsigned suf = L;                     // intra-wave inclusive suffix scan
            #pragma unroll
            for (int d = 1; d < 64; d <<= 1) {
                unsigned o = __shfl_down(suf, d, 64);
                if (lane + d < 64) suf += o;
            }
            if (lane == 0) scw[w] = suf;          // wave total
            BAR();                                                     // B3
            unsigned S = suf - L;                 // excl suffix within wave
            #pragma unroll
            for (int w2 = 1; w2 < 4; ++w2) if (w2 > (int)w) S += scw[w2];

            #pragma unroll
            for (int i = 7; i >= 0; --i) {
                unsigned h = hr[i], Sn = S + h;
                if (S < need && need <= Sn) { sh_selbin = 8u * t + i; sh_selS = S; }
                S = Sn;
            }
            BAR();                                                     // B4
            prefix = sh_selbin;                   // 11-bit prefix
            need -= sh_selS;
        }

        // ======== Pass 1: 2048 bins over key[20:10], prefix-filtered ========
        {
            // concurrently re-zero region A's first H10 words for pass 2
            uint4* hzA = reinterpret_cast<uint4*>(histA);
            #pragma unroll
            for (int i = 0; i < 2; ++i) {
                unsigned idx = t + NT * i;
                if (idx < H10 / 4) hzA[idx] = make_uint4(0u, 0u, 0u, 0u);
            }
            #pragma unroll
            for (int j = 0; j < EPT; ++j) {
                unsigned k = key[j];
                if ((k >> 21) == prefix) atomicAdd(&histB[pad8((k >> 10) & 0x7FFu)], 1u);
            }
            BAR();                                                     // B5

            unsigned hr[8];
            unsigned L = 0;
            const unsigned base = 9u * t;
            #pragma unroll
            for (int i = 0; i < 8; ++i) { hr[i] = histB[base + i]; L += hr[i]; }

            unsigned suf = L;
            #pragma unroll
            for (int d = 1; d < 64; d <<= 1) {
                unsigned o = __shfl_down(suf, d, 64);
                if (lane + d < 64) suf += o;
            }
            if (lane == 0) scw[w] = suf;
            BAR();                                                     // B6
            unsigned S = suf - L;
            #pragma unroll
            for (int w2 = 1; w2 < 4; ++w2) if (w2 > (int)w) S += scw[w2];

            #pragma unroll
            for (int i = 7; i >= 0; --i) {
                unsigned h = hr[i], Sn = S + h;
                if (S < need && need <= Sn) { sh_selbin = 8u * t + i; sh_selS = S; }
                S = Sn;
            }
            BAR();                                                     // B7
            prefix = (prefix << 11) | sh_selbin;  // 22-bit prefix
            need -= sh_selS;
        }

        // ======== Pass 2: 1024 bins over key[9:0], prefix-filtered ========
        {
            #pragma unroll
            for (int j = 0; j < EPT; ++j) {
                unsigned k = key[j];
                if ((k >> 10) == prefix) atomicAdd(&histA[pad4(k & 0x3FFu)], 1u);
            }
            BAR();                                                     // B8

            unsigned hr[4];
            unsigned L = 0;
            const unsigned base = 5u * t;         // pad4(4t+i) = 5t+i, i<4
            #pragma unroll
            for (int i = 0; i < 4; ++i) { hr[i] = histA[base + i]; L += hr[i]; }

            unsigned suf = L;
            #pragma unroll
            for (int d = 1; d < 64; d <<= 1) {
                unsigned o = __shfl_down(suf, d, 64);
                if (lane + d < 64) suf += o;
            }
            if (lane == 0) scw[w] = suf;
            BAR();                                                     // B9
            unsigned S = suf - L;
            #pragma unroll
            for (int w2 = 1; w2 < 4; ++w2) if (w2 > (int)w) S += scw[w2];

            #pragma unroll
            for (int i = 3; i >= 0; --i) {
                unsigned h = hr[i], Sn = S + h;
                if (S < need && need <= Sn) { sh_selbin = 4u * t + i; sh_selS = S; sh_selH = h; }
                S = Sn;
            }
            BAR();                                                     // B10
            T = (prefix << 10) | sh_selbin;       // full 32-bit threshold key
            need -= sh_selS;
        }
        const unsigned hsel = sh_selH;            // count of key == T in the row

        float4* ov = reinterpret_cast<float4*>(orow);

        if (need == hsel) {
            // ---- Common path (always, for distinct values): every tied
            // element is included, so inclusion is simply key >= T.
            // sh_* / histmem not touched again until after next row's B1/B3,
            // so no trailing barrier needed.
            #pragma unroll
            for (int c = 0; c < 4; ++c) {
                float rr[4];
                #pragma unroll
                for (int j = 0; j < 4; ++j) {
                    unsigned k = key[4 * c + j];
                    unsigned u = (k & 0x80000000u) ? (k ^ 0x80000000u) : ~k;
                    rr[j] = (k >= T) ? __uint_as_float(u) : 0.0f;
                }
                float4 o4;
                o4.x = rr[0]; o4.y = rr[1]; o4.z = rr[2]; o4.w = rr[3];
                ov[t + NT * c] = o4;   // plain store: L2 write-combines
            }
        } else {
            // ---- Rare exact tie-break (never taken for random-normal data):
            // first `need` of the key==T elements by global index, which is
            // (c, t, j) lexicographic. Register-light serial scan via LDS.
            // Block-uniform branch, so the barriers are safe.
            #pragma unroll
            for (int c = 0; c < 4; ++c) {
                unsigned e = 0;
                #pragma unroll
                for (int j = 0; j < 4; ++j) e += (key[4 * c + j] == T) ? 1u : 0u;
                histmem[c * NT + t] = e;
            }
            BAR();
            if (t == 0) {                          // serial exclusive scan, (c,t) order
                unsigned run = 0;
                for (int i = 0; i < 4 * NT; ++i) {
                    unsigned v = histmem[i];
                    histmem[i] = run;
                    run += v;
                }
            }
            BAR();
            #pragma unroll
            for (int c = 0; c < 4; ++c) {
                unsigned rank = histmem[c * NT + t];
                float rr[4];
                #pragma unroll
                for (int j = 0; j < 4; ++j) {
                    unsigned k = key[4 * c + j];
                    bool inc;
                    if (k > T)       inc = true;
                    else if (k == T) { inc = (rank < need); rank += 1u; }
                    else             inc = false;
                    unsigned u = (k & 0x80000000u) ? (k ^ 0x80000000u) : ~k;
                    rr[j] = inc ? __uint_as_float(u) : 0.0f;
                }
                float4 o4;
                o4.x = rr[0]; o4.y = rr[1]; o4.z = rr[2]; o4.w = rr[3];
                ov[t + NT * c] = o4;
            }
            BAR();   // protect this path's histmem reads from next-row zeroing
        }
    }
}

extern "C" void kernel_launch(void* const* d_in, const int* in_sizes, int n_in,
                              void* d_out, int out_size, void* d_ws, size_t ws_size,
                              hipStream_t stream) {
    const float* x = (const float*)d_in[0];
    float* out = (float*)d_out;
    const int rows = in_sizes[0] / COLS;  // 16384
    topk_mask_kernel<<<rows / RPB, NT, 0, stream>>>(x, out);
}

// Round 5
// 428.084 us; speedup vs baseline: 1.3306x; 1.1754x over previous
//
#include <hip/hip_runtime.h>

// TopK-mask: per row of [16384, 4096] f32, keep the 64 largest, zero the rest.
// One 256-thread block per row; keys = order-preserving uint32 transform.
// Radix select, digits 11+11(+10), MSB first, LDS histograms 2048/2048(/1024).
// Ties at the K-th value: lowest index wins (matches jax.lax.top_k).
//
// R8: revert R6/R7's persistent+prefetch experiment (VGPR spills: CSV reports
//   granules-of-2, 40 => 80 actual at the (256,6) cap, WRITE_SIZE 452MB vs 268
//   ideal, occupancy 58%, kernel 207us vs R5's <164). R5 structure restored.
//   NEW: early-exit radix. After pass 0/1, if need == h (threshold bin fully
//   included), the selection is resolved at that prefix granularity and the
//   remaining passes are skipped; inclusion is (key >> shift) >= P. For
//   random-normal rows the pass-1 bin holds ~1 element, so pass 2 (16
//   predicated compares, 4 LDS reads, 6-shfl scan, 3 barriers) is skipped
//   ~95% of the time. Zero extra register pressure; all branches are
//   block-uniform (broadcast via LDS), so barriers inside remain legal.
//
// R5 (kept): lane-contiguous float4 load/store (xv[t+256c]); tie-rank scan
//   off the common path; exact tie-break (need<h after pass 2) register-light.
//
// NOTE (R4 lesson): __builtin_nontemporal_store REGRESSED 3x (WRITE_SIZE
// 262->711MB). gfx950 'nt' bypasses L2 write-combining. Plain stores only.

#define COLS 4096
#define KTOP 64u
#define NT 256
#define EPT 16            // elements per thread (COLS / NT)
#define H11 2304          // 2048 bins + (b>>3) padding
#define H10 1280          // 1024 bins + (b>>2) padding (reuses region A)

__device__ __forceinline__ unsigned pad8(unsigned b) { return b + (b >> 3); }
__device__ __forceinline__ unsigned pad4(unsigned b) { return b + (b >> 2); }

__global__ __launch_bounds__(NT, 8) void topk_mask_kernel(const float* __restrict__ x,
                                                          float* __restrict__ out) {
    const int row = blockIdx.x;
    const int t = threadIdx.x;
    const unsigned lane = t & 63u;
    const unsigned w = t >> 6;

    const float* __restrict__ xr = x + (size_t)row * COLS;
    float* __restrict__ orow = out + (size_t)row * COLS;

    __shared__ alignas(16) unsigned histmem[2 * H11];  // A: [0,H11)  B: [H11,2*H11)
    __shared__ unsigned scw[4];
    __shared__ unsigned sh_selbin, sh_selS, sh_selH;

    unsigned* histA = histmem;
    unsigned* histB = histmem + H11;

    // ---- Coalesced load: thread t owns float4s {t, t+256, t+512, t+768} ----
    // Global element index of key[4c+j] is 1024*c + 4*t + j.
    unsigned key[EPT];
    const float4* xv = reinterpret_cast<const float4*>(xr);
    #pragma unroll
    for (int c = 0; c < 4; ++c) {
        float4 v = xv[t + NT * c];
        float f[4] = {v.x, v.y, v.z, v.w};
        #pragma unroll
        for (int j = 0; j < 4; ++j) {
            unsigned u = __float_as_uint(f[j]);
            key[4 * c + j] = (u & 0x80000000u) ? ~u : (u | 0x80000000u);
        }
    }

    // ---- Zero both histogram regions, vectorized ----
    {
        uint4* hz = reinterpret_cast<uint4*>(histmem);
        #pragma unroll
        for (int i = 0; i < 5; ++i) {
            unsigned idx = t + NT * i;
            if (idx < (2 * H11) / 4) hz[idx] = make_uint4(0u, 0u, 0u, 0u);
        }
    }
    __syncthreads();                                                   // B1

    unsigned need = KTOP;
    unsigned prefix = 0;

    // Final inclusion rule (common path): (key >> shiftv) >= P.
    unsigned shiftv = 0, P = 0;
    unsigned T = 0;
    bool rare = false;

    // ================= Pass 0: 2048 bins over key[31:21] =================
    #pragma unroll
    for (int j = 0; j < EPT; ++j) atomicAdd(&histA[pad8(key[j] >> 21)], 1u);
    __syncthreads();                                                   // B2
    {
        unsigned hr[8];
        unsigned L = 0;
        const unsigned base = 9u * t;             // pad8(8t+i) = 9t+i, i<8
        #pragma unroll
        for (int i = 0; i < 8; ++i) { hr[i] = histA[base + i]; L += hr[i]; }

        unsigned suf = L;                         // intra-wave inclusive suffix scan
        #pragma unroll
        for (int d = 1; d < 64; d <<= 1) {
            unsigned o = __shfl_down(suf, d, 64);
            if (lane + d < 64) suf += o;
        }
        if (lane == 0) scw[w] = suf;              // wave total
        __syncthreads();                                               // B3
        unsigned S = suf - L;                     // excl suffix within wave
        #pragma unroll
        for (int w2 = 1; w2 < 4; ++w2) if (w2 > (int)w) S += scw[w2];

        #pragma unroll
        for (int i = 7; i >= 0; --i) {
            unsigned h = hr[i], Sn = S + h;
            if (S < need && need <= Sn) { sh_selbin = 8u * t + i; sh_selS = S; sh_selH = h; }
            S = Sn;
        }
        __syncthreads();                                               // B4
        prefix = sh_selbin;                       // 11-bit prefix
        need -= sh_selS;
    }

    if (need == sh_selH) {
        // Threshold bin fully included at 11-bit granularity; done.
        shiftv = 21; P = prefix;
    } else {
        // ======== Pass 1: 2048 bins over key[20:10], prefix-filtered ========
        {
            // concurrently re-zero region A's first H10 words (used iff pass 2 runs)
            uint4* hzA = reinterpret_cast<uint4*>(histA);
            #pragma unroll
            for (int i = 0; i < 2; ++i) {
                unsigned idx = t + NT * i;
                if (idx < H10 / 4) hzA[idx] = make_uint4(0u, 0u, 0u, 0u);
            }
            #pragma unroll
            for (int j = 0; j < EPT; ++j) {
                unsigned k = key[j];
                if ((k >> 21) == prefix) atomicAdd(&histB[pad8((k >> 10) & 0x7FFu)], 1u);
            }
            __syncthreads();                                           // B5

            unsigned hr[8];
            unsigned L = 0;
            const unsigned base = 9u * t;
            #pragma unroll
            for (int i = 0; i < 8; ++i) { hr[i] = histB[base + i]; L += hr[i]; }

            unsigned suf = L;
            #pragma unroll
            for (int d = 1; d < 64; d <<= 1) {
                unsigned o = __shfl_down(suf, d, 64);
                if (lane + d < 64) suf += o;
            }
            if (lane == 0) scw[w] = suf;
            __syncthreads();                                           // B6
            unsigned S = suf - L;
            #pragma unroll
            for (int w2 = 1; w2 < 4; ++w2) if (w2 > (int)w) S += scw[w2];

            #pragma unroll
            for (int i = 7; i >= 0; --i) {
                unsigned h = hr[i], Sn = S + h;
                if (S < need && need <= Sn) { sh_selbin = 8u * t + i; sh_selS = S; sh_selH = h; }
                S = Sn;
            }
            __syncthreads();                                           // B7
            prefix = (prefix << 11) | sh_selbin;  // 22-bit prefix
            need -= sh_selS;
        }

        if (need == sh_selH) {
            // Threshold bin fully included at 22-bit granularity (typical for
            // random data: the bin holds exactly the threshold element). Done —
            // pass 2 skipped entirely.
            shiftv = 10; P = prefix;
        } else {
            // ======== Pass 2: 1024 bins over key[9:0], prefix-filtered ========
            #pragma unroll
            for (int j = 0; j < EPT; ++j) {
                unsigned k = key[j];
                if ((k >> 10) == prefix) atomicAdd(&histA[pad4(k & 0x3FFu)], 1u);
            }
            __syncthreads();                                           // B8

            unsigned hr[4];
            unsigned L = 0;
            const unsigned base = 5u * t;         // pad4(4t+i) = 5t+i, i<4
            #pragma unroll
            for (int i = 0; i < 4; ++i) { hr[i] = histA[base + i]; L += hr[i]; }

            unsigned suf = L;
            #pragma unroll
            for (int d = 1; d < 64; d <<= 1) {
                unsigned o = __shfl_down(suf, d, 64);
                if (lane + d < 64) suf += o;
            }
            if (lane == 0) scw[w] = suf;
            __syncthreads();                                           // B9
            unsigned S = suf - L;
            #pragma unroll
            for (int w2 = 1; w2 < 4; ++w2) if (w2 > (int)w) S += scw[w2];

            #pragma unroll
            for (int i = 3; i >= 0; --i) {
                unsigned h = hr[i], Sn = S + h;
                if (S < need && need <= Sn) { sh_selbin = 4u * t + i; sh_selS = S; sh_selH = h; }
                S = Sn;
            }
            __syncthreads();                                           // B10
            T = (prefix << 10) | sh_selbin;       // full 32-bit threshold key
            need -= sh_selS;
            shiftv = 0; P = T;
            rare = (need != sh_selH);             // true ties at T beyond quota
        }
    }

    float4* ov = reinterpret_cast<float4*>(orow);

    if (!rare) {
        // ---- Common path: inclusion is a prefix compare at the resolved
        // granularity. Covers the pass-0/pass-1 early exits and the exact
        // pass-2 threshold when all tied elements fit the quota.
        #pragma unroll
        for (int c = 0; c < 4; ++c) {
            float rr[4];
            #pragma unroll
            for (int j = 0; j < 4; ++j) {
                unsigned k = key[4 * c + j];
                unsigned u = (k & 0x80000000u) ? (k ^ 0x80000000u) : ~k;
                rr[j] = ((k >> shiftv) >= P) ? __uint_as_float(u) : 0.0f;
            }
            float4 o4;
            o4.x = rr[0]; o4.y = rr[1]; o4.z = rr[2]; o4.w = rr[3];
            ov[t + NT * c] = o4;   // plain store: L2 write-combines
        }
    } else {
        // ---- Rare exact tie-break (never taken for random-normal data):
        // first `need` of the key==T elements by global index, which is
        // (c, t, j) lexicographic. Register-light serial scan via LDS.
        // Block-uniform branch, so the barriers are safe.
        #pragma unroll
        for (int c = 0; c < 4; ++c) {
            unsigned e = 0;
            #pragma unroll
            for (int j = 0; j < 4; ++j) e += (key[4 * c + j] == T) ? 1u : 0u;
            histmem[c * NT + t] = e;
        }
        __syncthreads();
        if (t == 0) {                             // serial exclusive scan, (c,t) order
            unsigned run = 0;
            for (int i = 0; i < 4 * NT; ++i) {
                unsigned v = histmem[i];
                histmem[i] = run;
                run += v;
            }
        }
        __syncthreads();
        #pragma unroll
        for (int c = 0; c < 4; ++c) {
            unsigned rank = histmem[c * NT + t];
            float rr[4];
            #pragma unroll
            for (int j = 0; j < 4; ++j) {
                unsigned k = key[4 * c + j];
                bool inc;
                if (k > T)       inc = true;
                else if (k == T) { inc = (rank < need); rank += 1u; }
                else             inc = false;
                unsigned u = (k & 0x80000000u) ? (k ^ 0x80000000u) : ~k;
                rr[j] = inc ? __uint_as_float(u) : 0.0f;
            }
            float4 o4;
            o4.x = rr[0]; o4.y = rr[1]; o4.z = rr[2]; o4.w = rr[3];
            ov[t + NT * c] = o4;
        }
    }
}

extern "C" void kernel_launch(void* const* d_in, const int* in_sizes, int n_in,
                              void* d_out, int out_size, void* d_ws, size_t ws_size,
                              hipStream_t stream) {
    const float* x = (const float*)d_in[0];
    float* out = (float*)d_out;
    const int rows = in_sizes[0] / COLS;  // 16384
    topk_mask_kernel<<<rows, NT, 0, stream>>>(x, out);
}